// Round 1
// baseline (441.076 us; speedup 1.0000x reference)
//
#include <hip/hip_runtime.h>
#include <hip/hip_bf16.h>

#define NODES 50000
#define EDGES 800000
#define DIN   19
#define HDIM  64
#define LAYERS 3
#define BN_EPS 1e-5f

typedef __attribute__((ext_vector_type(4))) float f32x4;
typedef __attribute__((ext_vector_type(8))) short s16x8;

// ---------------- CSR build ----------------

__global__ void k_hist(const int* __restrict__ dst, int* __restrict__ deg) {
    int i = blockIdx.x * blockDim.x + threadIdx.x;
    if (i < EDGES) atomicAdd(&deg[dst[i]], 1);
}

// single-block hierarchical exclusive scan of deg -> off[N+1]; also rdenom = 1/max(deg,1)
__global__ void k_scan(const int* __restrict__ deg, int* __restrict__ off,
                       float* __restrict__ rdenom) {
    __shared__ int wsum[16];
    __shared__ int carry_s;
    int tid = threadIdx.x, lane = tid & 63, wid = tid >> 6;
    if (tid == 0) { carry_s = 0; off[0] = 0; }
    __syncthreads();
    for (int base = 0; base < NODES; base += 16384) {
        int my0 = base + tid * 16;
        int v[16];
        int s = 0;
        #pragma unroll
        for (int i = 0; i < 16; ++i) {
            int idx = my0 + i;
            int d = (idx < NODES) ? deg[idx] : 0;
            v[i] = d; s += d;
        }
        int inc = s;
        #pragma unroll
        for (int d = 1; d < 64; d <<= 1) {
            int t = __shfl_up(inc, d);
            if (lane >= d) inc += t;
        }
        if (lane == 63) wsum[wid] = inc;
        __syncthreads();
        if (wid == 0 && lane < 16) {
            int t = wsum[lane];
            #pragma unroll
            for (int d = 1; d < 16; d <<= 1) {
                int u = __shfl_up(t, d);
                if (lane >= d) t += u;
            }
            wsum[lane] = t;
        }
        __syncthreads();
        int carry = carry_s;
        int pre = carry + (wid ? wsum[wid - 1] : 0) + (inc - s);
        #pragma unroll
        for (int i = 0; i < 16; ++i) {
            int idx = my0 + i;
            if (idx < NODES) {
                pre += v[i];
                off[idx + 1] = pre;
                rdenom[idx] = 1.0f / fmaxf((float)v[i], 1.0f);
            }
        }
        int total = wsum[15];
        __syncthreads();
        if (tid == 0) carry_s = carry + total;
    }
}

__global__ void k_scatter(const int* __restrict__ src, const int* __restrict__ dst,
                          const int* __restrict__ off, int* __restrict__ cursor,
                          int* __restrict__ ebuf) {
    int i = blockIdx.x * blockDim.x + threadIdx.x;
    if (i < EDGES) {
        int d = dst[i];
        int slot = atomicAdd(&cursor[d], 1);
        ebuf[off[d] + slot] = src[i];
    }
}

// ---------------- weight / input prep (fp32 -> bf16, transposed) ----------------

// WiT[c][k] (64 x 32, k>=19 zero-padded); WcatT[l][c][k] (64 x 128) = [wl;wr]^T
__global__ void k_wprep(const float* __restrict__ w_in, const float* __restrict__ wl,
                        const float* __restrict__ wr,
                        __hip_bfloat16* __restrict__ WiT, __hip_bfloat16* __restrict__ WcatT) {
    int i = blockIdx.x * blockDim.x + threadIdx.x;
    if (i < 64 * 32) {
        int c = i >> 5, k = i & 31;
        WiT[i] = __float2bfloat16(k < DIN ? w_in[k * HDIM + c] : 0.0f);
    }
    if (i < LAYERS * 64 * 128) {
        int l = i >> 13;
        int rem = i & 8191;
        int c = rem >> 7, k = rem & 127;
        float v = (k < 64) ? wl[(l * 64 + k) * 64 + c] : wr[(l * 64 + (k - 64)) * 64 + c];
        WcatT[i] = __float2bfloat16(v);
    }
}

__global__ void k_xpad(const float* __restrict__ x, __hip_bfloat16* __restrict__ xpad) {
    int i = blockIdx.x * blockDim.x + threadIdx.x;
    if (i < NODES * 32) {
        int n = i >> 5, k = i & 31;
        xpad[i] = __float2bfloat16(k < DIN ? x[n * DIN + k] : 0.0f);
    }
}

// ---------------- GEMM: C[M,64] = A[M,K](bf16) @ W[K,64](bf16, stored transposed WT[64][K]) + bias ----------------

__global__ void k_gemm(const __hip_bfloat16* __restrict__ A, int lda,
                       const __hip_bfloat16* __restrict__ WT, int K,
                       const float* __restrict__ bias, float* __restrict__ C) {
    int lane = threadIdx.x & 63, wave = threadIdx.x >> 6;
    int row0 = blockIdx.x * 64 + wave * 16;
    int r = lane & 15, g = lane >> 4;
    f32x4 acc[4] = {{0.f,0.f,0.f,0.f},{0.f,0.f,0.f,0.f},{0.f,0.f,0.f,0.f},{0.f,0.f,0.f,0.f}};
    int ar = row0 + r;
    if (ar >= NODES) ar = NODES - 1;
    for (int k0 = 0; k0 < K; k0 += 32) {
        s16x8 af = *(const s16x8*)(A + (size_t)ar * lda + k0 + g * 8);
        #pragma unroll
        for (int j = 0; j < 4; ++j) {
            s16x8 bf = *(const s16x8*)(WT + (size_t)(j * 16 + r) * K + k0 + g * 8);
            acc[j] = __builtin_amdgcn_mfma_f32_16x16x32_bf16(af, bf, acc[j], 0, 0, 0);
        }
    }
    #pragma unroll
    for (int j = 0; j < 4; ++j) {
        float b = bias[j * 16 + r];
        #pragma unroll
        for (int i = 0; i < 4; ++i) {
            int row = row0 + g * 4 + i;
            if (row < NODES) C[(size_t)row * 64 + j * 16 + r] = acc[j][i] + b;
        }
    }
}

// ---------------- BN stats: per-feature sum & sumsq ----------------

__global__ void k_stats(const float* __restrict__ t, float* __restrict__ stats) {
    int j = threadIdx.x & 63;
    int w = blockIdx.x * (blockDim.x >> 6) + (threadIdx.x >> 6);
    int nw = gridDim.x * (blockDim.x >> 6);
    float s = 0.0f, q = 0.0f;
    for (int n = w; n < NODES; n += nw) {
        float v = t[(size_t)n * 64 + j];
        s += v; q += v * v;
    }
    atomicAdd(&stats[j], s);
    atomicAdd(&stats[64 + j], q);
}

// ---------------- BN finalize + ReLU (+residual), write h (fp32) and bf16 mirror into AB[:,64:128] ----------------

__global__ void k_apply(const float* __restrict__ t, const float* __restrict__ stats,
                        const float* __restrict__ gamma, const float* __restrict__ beta,
                        float* __restrict__ h, __hip_bfloat16* __restrict__ AB, int residual) {
    int idx0 = blockIdx.x * blockDim.x + threadIdx.x;
    int stride = gridDim.x * blockDim.x;
    const float invN = 1.0f / NODES;
    for (int idx = idx0; idx < NODES * HDIM; idx += stride) {
        int j = idx & 63;
        float mu = stats[j] * invN;
        float var = stats[64 + j] * invN - mu * mu;
        float sc = gamma[j] * rsqrtf(var + BN_EPS);
        float sh = beta[j] - mu * sc;
        float v = fmaxf(t[idx] * sc + sh, 0.0f);
        float hn = residual ? (h[idx] + v) : v;
        h[idx] = hn;
        AB[(size_t)(idx >> 6) * 128 + 64 + j] = __float2bfloat16(hn);
    }
}

// ---------------- mean aggregation: AB[:,0:64] = mean of AB[src,64:128] over in-edges ----------------

__global__ void k_agg(const int* __restrict__ off, const int* __restrict__ ebuf,
                      const float* __restrict__ rdenom, __hip_bfloat16* __restrict__ AB) {
    int lane = threadIdx.x & 63;
    int w = blockIdx.x * (blockDim.x >> 6) + (threadIdx.x >> 6);
    int nw = gridDim.x * (blockDim.x >> 6);
    for (int n = w; n < NODES; n += nw) {
        int p0 = off[n], p1 = off[n + 1];
        float a = 0.0f;
        #pragma unroll 4
        for (int p = p0; p < p1; ++p) {
            int s = ebuf[p];
            a += __bfloat162float(AB[(size_t)s * 128 + 64 + lane]);
        }
        a *= rdenom[n];
        AB[(size_t)n * 128 + lane] = __float2bfloat16(a);
    }
}

// ---------------- launch ----------------

extern "C" void kernel_launch(void* const* d_in, const int* in_sizes, int n_in,
                              void* d_out, int out_size, void* d_ws, size_t ws_size,
                              hipStream_t stream) {
    const float* x    = (const float*)d_in[0];
    const int*   ei   = (const int*)d_in[1];
    const float* w_in = (const float*)d_in[2];
    const float* b_in = (const float*)d_in[3];
    const float* bn0g = (const float*)d_in[4];
    const float* bn0b = (const float*)d_in[5];
    const float* wl   = (const float*)d_in[6];
    const float* bl   = (const float*)d_in[7];
    const float* wr   = (const float*)d_in[8];
    const float* bng  = (const float*)d_in[9];
    const float* bnb  = (const float*)d_in[10];
    const int* esrc = ei;
    const int* edst = ei + EDGES;
    float* h = (float*)d_out;

    char* p = (char*)d_ws;
    auto alloc = [&](size_t bytes) {
        char* r = p;
        p += (bytes + 255) & ~size_t(255);
        return r;
    };
    int*   deg    = (int*)alloc((size_t)NODES * 4);
    int*   cursor = (int*)alloc((size_t)NODES * 4);
    float* stats  = (float*)alloc(512 * 4);
    char*  zero_end = p;
    int*   off    = (int*)alloc((size_t)(NODES + 1) * 4);
    float* rden   = (float*)alloc((size_t)NODES * 4);
    int*   ebuf   = (int*)alloc((size_t)EDGES * 4);
    __hip_bfloat16* xpad  = (__hip_bfloat16*)alloc((size_t)NODES * 32 * 2);
    __hip_bfloat16* WiT   = (__hip_bfloat16*)alloc(64 * 32 * 2);
    __hip_bfloat16* WcatT = (__hip_bfloat16*)alloc(LAYERS * 64 * 128 * 2);
    __hip_bfloat16* AB    = (__hip_bfloat16*)alloc((size_t)NODES * 128 * 2);
    float* t = (float*)alloc((size_t)NODES * 64 * 4);

    hipMemsetAsync(deg, 0, (size_t)(zero_end - (char*)deg), stream);

    k_hist<<<(EDGES + 255) / 256, 256, 0, stream>>>(edst, deg);
    k_scan<<<1, 1024, 0, stream>>>(deg, off, rden);
    k_scatter<<<(EDGES + 255) / 256, 256, 0, stream>>>(esrc, edst, off, cursor, ebuf);
    k_wprep<<<(LAYERS * 64 * 128 + 255) / 256, 256, 0, stream>>>(w_in, wl, wr, WiT, WcatT);
    k_xpad<<<(NODES * 32 + 255) / 256, 256, 0, stream>>>(x, xpad);

    // input projection -> t
    k_gemm<<<(NODES + 63) / 64, 256, 0, stream>>>(xpad, 32, WiT, 32, b_in, t);
    k_stats<<<256, 256, 0, stream>>>(t, stats);
    k_apply<<<2048, 256, 0, stream>>>(t, stats, bn0g, bn0b, h, AB, 0);

    for (int l = 0; l < LAYERS; ++l) {
        k_agg<<<2048, 256, 0, stream>>>(off, ebuf, rden, AB);
        k_gemm<<<(NODES + 63) / 64, 256, 0, stream>>>(AB, 128, WcatT + l * 8192, 128, bl + l * 64, t);
        k_stats<<<256, 256, 0, stream>>>(t, stats + 128 * (l + 1));
        k_apply<<<2048, 256, 0, stream>>>(t, stats + 128 * (l + 1), bng + l * 64, bnb + l * 64, h, AB, 1);
    }
}

// Round 2
// 398.114 us; speedup vs baseline: 1.1079x; 1.1079x over previous
//
#include <hip/hip_runtime.h>
#include <hip/hip_bf16.h>

#define NODES 50000
#define EDGES 800000
#define DIN   19
#define HDIM  64
#define LAYERS 3
#define BN_EPS 1e-5f

#define NBINS 196      // ceil(NODES / 256)
#define SUBS  8
#define CAP   640      // per-(bin,sub) capacity; mean ~510, +7 sigma

typedef __attribute__((ext_vector_type(4))) float f32x4;
typedef __attribute__((ext_vector_type(8))) short s16x8;

// ---------------- edge binning pass A: histogram deg + bin edges by dst>>8 ----------------

__global__ void k_binA(const int* __restrict__ src, const int* __restrict__ dst,
                       int* __restrict__ deg, int* __restrict__ bcur, int2* __restrict__ bbuf) {
    int i = blockIdx.x * blockDim.x + threadIdx.x;
    if (i >= EDGES) return;
    int s = src[i], d = dst[i];
    atomicAdd(&deg[d], 1);
    int c = (d >> 8) * SUBS + (blockIdx.x & 7);
    int slot = atomicAdd(&bcur[c * 16], 1);   // counters padded to 64B lines
    if (slot < CAP) bbuf[(size_t)c * CAP + slot] = make_int2(d, s);
}

// single-block hierarchical exclusive scan of deg -> off[N+1]; also rdenom = 1/max(deg,1)
__global__ void k_scan(const int* __restrict__ deg, int* __restrict__ off,
                       float* __restrict__ rdenom) {
    __shared__ int wsum[16];
    __shared__ int carry_s;
    int tid = threadIdx.x, lane = tid & 63, wid = tid >> 6;
    if (tid == 0) { carry_s = 0; off[0] = 0; }
    __syncthreads();
    for (int base = 0; base < NODES; base += 16384) {
        int my0 = base + tid * 16;
        int v[16];
        int s = 0;
        #pragma unroll
        for (int i = 0; i < 16; ++i) {
            int idx = my0 + i;
            int d = (idx < NODES) ? deg[idx] : 0;
            v[i] = d; s += d;
        }
        int inc = s;
        #pragma unroll
        for (int d = 1; d < 64; d <<= 1) {
            int t = __shfl_up(inc, d);
            if (lane >= d) inc += t;
        }
        if (lane == 63) wsum[wid] = inc;
        __syncthreads();
        if (wid == 0 && lane < 16) {
            int t = wsum[lane];
            #pragma unroll
            for (int d = 1; d < 16; d <<= 1) {
                int u = __shfl_up(t, d);
                if (lane >= d) t += u;
            }
            wsum[lane] = t;
        }
        __syncthreads();
        int carry = carry_s;
        int pre = carry + (wid ? wsum[wid - 1] : 0) + (inc - s);
        #pragma unroll
        for (int i = 0; i < 16; ++i) {
            int idx = my0 + i;
            if (idx < NODES) {
                pre += v[i];
                off[idx + 1] = pre;
                rdenom[idx] = 1.0f / fmaxf((float)v[i], 1.0f);
            }
        }
        int total = wsum[15];
        __syncthreads();
        if (tid == 0) carry_s = carry + total;
    }
}

// ---------------- pass B: per-bin scatter into CSR with LDS cursors ----------------

__global__ void k_binB(const int* __restrict__ bcur, const int2* __restrict__ bbuf,
                       const int* __restrict__ off, int* __restrict__ ebuf) {
    __shared__ int cur[256];
    int bin = blockIdx.x;
    int base_node = bin << 8;
    for (int t = threadIdx.x; t < 256; t += blockDim.x) cur[t] = 0;
    __syncthreads();
    #pragma unroll
    for (int sub = 0; sub < SUBS; ++sub) {
        int c = bin * SUBS + sub;
        int cnt = min(bcur[c * 16], CAP);
        const int2* bp = bbuf + (size_t)c * CAP;
        for (int idx = threadIdx.x; idx < cnt; idx += blockDim.x) {
            int2 e = bp[idx];
            int slot = atomicAdd(&cur[e.x - base_node], 1);
            ebuf[off[e.x] + slot] = e.y;
        }
    }
}

// ---------------- prep: weights fp32->bf16 transposed, x padded bf16 ----------------

__global__ void k_prep(const float* __restrict__ x, const float* __restrict__ w_in,
                       const float* __restrict__ wl, const float* __restrict__ wr,
                       __hip_bfloat16* __restrict__ xpad, __hip_bfloat16* __restrict__ WiT,
                       __hip_bfloat16* __restrict__ WcatT) {
    int i = blockIdx.x * blockDim.x + threadIdx.x;
    if (i < 64 * 32) {
        int c = i >> 5, k = i & 31;
        WiT[i] = __float2bfloat16(k < DIN ? w_in[k * HDIM + c] : 0.0f);
    }
    if (i < LAYERS * 64 * 128) {
        int l = i >> 13;
        int rem = i & 8191;
        int c = rem >> 7, k = rem & 127;
        float v = (k < 64) ? wl[(l * 64 + k) * 64 + c] : wr[(l * 64 + (k - 64)) * 64 + c];
        WcatT[i] = __float2bfloat16(v);
    }
    if (i < NODES * 32) {
        int n = i >> 5, k = i & 31;
        xpad[i] = __float2bfloat16(k < DIN ? x[n * DIN + k] : 0.0f);
    }
}

// ---------------- GEMM + fused BN stats ----------------
// C[M,64] = A[M,K](bf16) @ W[K,64] (stored WT[64][K] bf16) + bias; stats_pad[f*16] += {sum, sumsq}

__global__ void k_gemm(const __hip_bfloat16* __restrict__ A, int lda,
                       const __hip_bfloat16* __restrict__ WT, int K,
                       const float* __restrict__ bias, float* __restrict__ C,
                       float* __restrict__ stats) {
    __shared__ float red[4][128];
    int lane = threadIdx.x & 63, wave = threadIdx.x >> 6;
    int row0 = blockIdx.x * 64 + wave * 16;
    int r = lane & 15, g = lane >> 4;
    f32x4 acc[4] = {{0.f,0.f,0.f,0.f},{0.f,0.f,0.f,0.f},{0.f,0.f,0.f,0.f},{0.f,0.f,0.f,0.f}};
    int ar = row0 + r;
    if (ar >= NODES) ar = NODES - 1;
    for (int k0 = 0; k0 < K; k0 += 32) {
        s16x8 af = *(const s16x8*)(A + (size_t)ar * lda + k0 + g * 8);
        #pragma unroll
        for (int j = 0; j < 4; ++j) {
            s16x8 bf = *(const s16x8*)(WT + (size_t)(j * 16 + r) * K + k0 + g * 8);
            acc[j] = __builtin_amdgcn_mfma_f32_16x16x32_bf16(af, bf, acc[j], 0, 0, 0);
        }
    }
    float s_[4], q_[4];
    #pragma unroll
    for (int j = 0; j < 4; ++j) {
        float b = bias[j * 16 + r];
        float s = 0.0f, q = 0.0f;
        #pragma unroll
        for (int i = 0; i < 4; ++i) {
            int row = row0 + g * 4 + i;
            if (row < NODES) {
                float v = acc[j][i] + b;
                C[(size_t)row * 64 + j * 16 + r] = v;
                s += v; q += v * v;
            }
        }
        s += __shfl_xor(s, 16); s += __shfl_xor(s, 32);
        q += __shfl_xor(q, 16); q += __shfl_xor(q, 32);
        s_[j] = s; q_[j] = q;
    }
    if (g == 0) {
        #pragma unroll
        for (int j = 0; j < 4; ++j) {
            red[wave][j * 16 + r] = s_[j];
            red[wave][64 + j * 16 + r] = q_[j];
        }
    }
    __syncthreads();
    if (threadIdx.x < 128) {
        float tot = red[0][threadIdx.x] + red[1][threadIdx.x] +
                    red[2][threadIdx.x] + red[3][threadIdx.x];
        atomicAdd(&stats[threadIdx.x * 16], tot);   // one 64B line per feature
    }
}

// ---------------- BN finalize + ReLU (+residual) -> h fp32, bf16 mirror AB[:,64:128] ----------------

__global__ void k_apply(const float* __restrict__ t, const float* __restrict__ stats,
                        const float* __restrict__ gamma, const float* __restrict__ beta,
                        float* __restrict__ h, __hip_bfloat16* __restrict__ AB, int residual) {
    int idx0 = blockIdx.x * blockDim.x + threadIdx.x;
    int stride = gridDim.x * blockDim.x;
    const float invN = 1.0f / NODES;
    for (int idx = idx0; idx < NODES * HDIM; idx += stride) {
        int j = idx & 63;
        float mu = stats[j * 16] * invN;
        float var = stats[(64 + j) * 16] * invN - mu * mu;
        float sc = gamma[j] * rsqrtf(var + BN_EPS);
        float sh = beta[j] - mu * sc;
        float v = fmaxf(t[idx] * sc + sh, 0.0f);
        float hn = residual ? (h[idx] + v) : v;
        h[idx] = hn;
        AB[(size_t)(idx >> 6) * 128 + 64 + j] = __float2bfloat16(hn);
    }
}

// ---------------- mean aggregation: AB[:,0:64] = mean over in-edges of AB[src,64:128] ----------------

__global__ void k_agg(const int* __restrict__ off, const int* __restrict__ ebuf,
                      const float* __restrict__ rdenom, __hip_bfloat16* __restrict__ AB) {
    int lane = threadIdx.x & 63;
    int w = blockIdx.x * (blockDim.x >> 6) + (threadIdx.x >> 6);
    int nw = gridDim.x * (blockDim.x >> 6);
    for (int n = w; n < NODES; n += nw) {
        int p0 = off[n], p1 = off[n + 1];
        float a = 0.0f;
        #pragma unroll 4
        for (int p = p0; p < p1; ++p) {
            int s = ebuf[p];
            a += __bfloat162float(AB[(size_t)s * 128 + 64 + lane]);
        }
        a *= rdenom[n];
        AB[(size_t)n * 128 + lane] = __float2bfloat16(a);
    }
}

// ---------------- launch ----------------

extern "C" void kernel_launch(void* const* d_in, const int* in_sizes, int n_in,
                              void* d_out, int out_size, void* d_ws, size_t ws_size,
                              hipStream_t stream) {
    const float* x    = (const float*)d_in[0];
    const int*   ei   = (const int*)d_in[1];
    const float* w_in = (const float*)d_in[2];
    const float* b_in = (const float*)d_in[3];
    const float* bn0g = (const float*)d_in[4];
    const float* bn0b = (const float*)d_in[5];
    const float* wl   = (const float*)d_in[6];
    const float* bl   = (const float*)d_in[7];
    const float* wr   = (const float*)d_in[8];
    const float* bng  = (const float*)d_in[9];
    const float* bnb  = (const float*)d_in[10];
    const int* esrc = ei;
    const int* edst = ei + EDGES;
    float* h = (float*)d_out;

    char* p = (char*)d_ws;
    auto alloc = [&](size_t bytes) {
        char* r = p;
        p += (bytes + 255) & ~size_t(255);
        return r;
    };
    // zeroed region
    int*   deg   = (int*)alloc((size_t)NODES * 4);
    int*   bcur  = (int*)alloc((size_t)NBINS * SUBS * 16 * 4);
    float* stats = (float*)alloc((size_t)4 * 128 * 16 * 4);
    char*  zero_end = p;
    // scratch
    int*   off  = (int*)alloc((size_t)(NODES + 1) * 4);
    float* rden = (float*)alloc((size_t)NODES * 4);
    int*   ebuf = (int*)alloc((size_t)EDGES * 4);
    int2*  bbuf = (int2*)alloc((size_t)NBINS * SUBS * CAP * 8);
    __hip_bfloat16* xpad  = (__hip_bfloat16*)alloc((size_t)NODES * 32 * 2);
    __hip_bfloat16* WiT   = (__hip_bfloat16*)alloc(64 * 32 * 2);
    __hip_bfloat16* WcatT = (__hip_bfloat16*)alloc(LAYERS * 64 * 128 * 2);
    __hip_bfloat16* AB    = (__hip_bfloat16*)alloc((size_t)NODES * 128 * 2);
    float* t = (float*)alloc((size_t)NODES * 64 * 4);

    hipMemsetAsync(deg, 0, (size_t)(zero_end - (char*)deg), stream);

    k_binA<<<(EDGES + 255) / 256, 256, 0, stream>>>(esrc, edst, deg, bcur, bbuf);
    k_scan<<<1, 1024, 0, stream>>>(deg, off, rden);
    k_binB<<<NBINS, 256, 0, stream>>>(bcur, bbuf, off, ebuf);
    k_prep<<<(NODES * 32 + 255) / 256, 256, 0, stream>>>(x, w_in, wl, wr, xpad, WiT, WcatT);

    k_gemm<<<(NODES + 63) / 64, 256, 0, stream>>>(xpad, 32, WiT, 32, b_in, t, stats);
    k_apply<<<2048, 256, 0, stream>>>(t, stats, bn0g, bn0b, h, AB, 0);

    for (int l = 0; l < LAYERS; ++l) {
        k_agg<<<2048, 256, 0, stream>>>(off, ebuf, rden, AB);
        k_gemm<<<(NODES + 63) / 64, 256, 0, stream>>>(AB, 128, WcatT + l * 8192, 128,
                                                      bl + l * 64, t, stats + (l + 1) * 2048);
        k_apply<<<2048, 256, 0, stream>>>(t, stats + (l + 1) * 2048, bng + l * 64, bnb + l * 64,
                                          h, AB, 1);
    }
}

// Round 3
// 358.299 us; speedup vs baseline: 1.2310x; 1.1111x over previous
//
#include <hip/hip_runtime.h>
#include <hip/hip_bf16.h>

#define NODES 50000
#define EDGES 800000
#define DIN   19
#define HDIM  64
#define LAYERS 3
#define BN_EPS 1e-5f

#define NBINS 196          // ceil(NODES/256), bin = dst>>8
#define EPB   4096         // edges per sort block
#define NBLK  196          // ceil(EDGES/EPB)

typedef __attribute__((ext_vector_type(4))) float f32x4;
typedef __attribute__((ext_vector_type(8))) short s16x8;

__device__ inline ushort bf16bits(float f) {
    __hip_bfloat16 h = __float2bfloat16(f);
    return *reinterpret_cast<ushort*>(&h);
}
__device__ inline float bf16lo(unsigned v) { return __uint_as_float(v << 16); }
__device__ inline float bf16hi(unsigned v) { return __uint_as_float(v & 0xFFFF0000u); }

// ---------------- pass A: per-block LDS counting sort of edges by dst>>8 ----------------
// bbuf[blk*EPB .. +ne) = edges of block blk grouped by bin, entry = (dst&255)<<24 | src
// cb[bin*NBLK+blk] = (segment offset within block region, count)

__global__ __launch_bounds__(1024) void k_sortA(const int* __restrict__ src, const int* __restrict__ dst,
                                                int2* __restrict__ cb, int* __restrict__ bintot,
                                                unsigned* __restrict__ bbuf) {
    __shared__ int hist[256];
    __shared__ int cur[256];
    __shared__ int wsum4[4];
    __shared__ unsigned stage[EPB];
    int blk = blockIdx.x, t = threadIdx.x;
    int e0 = blk * EPB;
    int ne = min(EPB, EDGES - e0);
    int d[4]; unsigned pk[4];
    #pragma unroll
    for (int i = 0; i < 4; ++i) {
        int j = t + i * 1024;
        if (j < ne) {
            int dd = dst[e0 + j];
            d[i] = dd;
            pk[i] = ((unsigned)(dd & 255) << 24) | (unsigned)src[e0 + j];
        } else d[i] = -1;
    }
    if (t < 256) hist[t] = 0;
    __syncthreads();
    #pragma unroll
    for (int i = 0; i < 4; ++i)
        if (d[i] >= 0) atomicAdd(&hist[d[i] >> 8], 1);
    __syncthreads();
    // exclusive scan of hist[0..255] using 4 waves
    int ln = t & 63, wv = t >> 6;
    int cntv = 0, inc = 0;
    if (t < 256) {
        cntv = hist[t];
        inc = cntv;
        #pragma unroll
        for (int s = 1; s < 64; s <<= 1) {
            int u = __shfl_up(inc, s);
            if (ln >= s) inc += u;
        }
        if (ln == 63) wsum4[wv] = inc;
    }
    __syncthreads();
    if (t < 256) {
        int woff = 0;
        #pragma unroll
        for (int i = 0; i < 4; ++i) if (i < wv) woff += wsum4[i];
        int excl = woff + inc - cntv;
        cur[t] = excl;
        if (t < NBINS) {
            cb[t * NBLK + blk] = make_int2(excl, cntv);
            if (cntv) atomicAdd(&bintot[t], cntv);
        }
    }
    __syncthreads();
    #pragma unroll
    for (int i = 0; i < 4; ++i)
        if (d[i] >= 0) {
            int slot = atomicAdd(&cur[d[i] >> 8], 1);
            stage[slot] = pk[i];
        }
    __syncthreads();
    #pragma unroll
    for (int i = 0; i < 4; ++i) {
        int j = t + i * 1024;
        if (j < ne) bbuf[e0 + j] = stage[j];
    }
}

// ---------------- pass B: per-bin CSR assembly ----------------
// writes off[], rdenom[], ebuf[] (bin regions are contiguous => global CSR)

__global__ __launch_bounds__(512) void k_binB(const int2* __restrict__ cb, const int* __restrict__ bintot,
                                              const unsigned* __restrict__ bbuf,
                                              int* __restrict__ off, float* __restrict__ rdenom,
                                              int* __restrict__ ebuf) {
    __shared__ int red[256];
    __shared__ int segoff[NBINS], segcnt[NBINS];
    __shared__ int deg[256], loff[256], cur[256];
    __shared__ int wsum4[4];
    __shared__ int binoff_s;
    int b = blockIdx.x, t = threadIdx.x;
    int ln = t & 63, wv = t >> 6;
    // binoff = sum of bintot[i<b]
    if (t < 256) red[t] = (t < b) ? bintot[t] : 0;
    __syncthreads();
    #pragma unroll
    for (int s = 128; s > 0; s >>= 1) {
        if (t < s && t + s < 256) red[t] += red[t + s];
        __syncthreads();
    }
    if (t == 0) binoff_s = red[0];
    if (t < NBINS) {
        int2 c = cb[b * NBLK + t];
        segoff[t] = c.x; segcnt[t] = c.y;
    }
    if (t < 256) { deg[t] = 0; cur[t] = 0; }
    __syncthreads();
    int binoff = binoff_s;
    // pass 1: per-node degree
    for (int sg = wv; sg < NBLK; sg += 8) {
        int c = segcnt[sg];
        const unsigned* bp = bbuf + sg * EPB + segoff[sg];
        for (int k = ln; k < c; k += 64) atomicAdd(&deg[bp[k] >> 24], 1);
    }
    __syncthreads();
    // scan deg -> loff (exclusive, 256 entries via 4 waves)
    int dv = 0, inc = 0;
    if (t < 256) {
        dv = deg[t];
        inc = dv;
        #pragma unroll
        for (int s = 1; s < 64; s <<= 1) {
            int u = __shfl_up(inc, s);
            if (ln >= s) inc += u;
        }
        if (ln == 63) wsum4[wv] = inc;
    }
    __syncthreads();
    if (t < 256) {
        int woff = 0;
        #pragma unroll
        for (int i = 0; i < 4; ++i) if (i < wv) woff += wsum4[i];
        int excl = woff + inc - dv;
        loff[t] = excl;
        int node = (b << 8) + t;
        if (node < NODES) {
            off[node] = binoff + excl;
            rdenom[node] = 1.0f / fmaxf((float)dv, 1.0f);
        }
        if (b == NBINS - 1 && t == 0) off[NODES] = EDGES;
    }
    __syncthreads();
    // pass 2: scatter into ebuf
    for (int sg = wv; sg < NBLK; sg += 8) {
        int c = segcnt[sg];
        const unsigned* bp = bbuf + sg * EPB + segoff[sg];
        for (int k = ln; k < c; k += 64) {
            unsigned e = bp[k];
            int dd = e >> 24;
            int slot = atomicAdd(&cur[dd], 1);
            ebuf[binoff + loff[dd] + slot] = (int)(e & 0xFFFFFFu);
        }
    }
}

// ---------------- prep: weights fp32->bf16 transposed, x padded bf16 ----------------

__global__ void k_prep(const float* __restrict__ x, const float* __restrict__ w_in,
                       const float* __restrict__ wl, const float* __restrict__ wr,
                       __hip_bfloat16* __restrict__ xpad, __hip_bfloat16* __restrict__ WiT,
                       __hip_bfloat16* __restrict__ WcatT) {
    int i = blockIdx.x * blockDim.x + threadIdx.x;
    if (i < 64 * 32) {
        int c = i >> 5, k = i & 31;
        WiT[i] = __float2bfloat16(k < DIN ? w_in[k * HDIM + c] : 0.0f);
    }
    if (i < LAYERS * 64 * 128) {
        int l = i >> 13;
        int rem = i & 8191;
        int c = rem >> 7, k = rem & 127;
        float v = (k < 64) ? wl[(l * 64 + k) * 64 + c] : wr[(l * 64 + (k - 64)) * 64 + c];
        WcatT[i] = __float2bfloat16(v);
    }
    if (i < NODES * 32) {
        int n = i >> 5, k = i & 31;
        xpad[i] = __float2bfloat16(k < DIN ? x[n * DIN + k] : 0.0f);
    }
}

// ---------------- GEMM + fused BN stats ----------------

__global__ void k_gemm(const __hip_bfloat16* __restrict__ A, int lda,
                       const __hip_bfloat16* __restrict__ WT, int K,
                       const float* __restrict__ bias, float* __restrict__ C,
                       float* __restrict__ stats) {
    __shared__ float red[4][128];
    int lane = threadIdx.x & 63, wave = threadIdx.x >> 6;
    int row0 = blockIdx.x * 64 + wave * 16;
    int r = lane & 15, g = lane >> 4;
    f32x4 acc[4] = {{0.f,0.f,0.f,0.f},{0.f,0.f,0.f,0.f},{0.f,0.f,0.f,0.f},{0.f,0.f,0.f,0.f}};
    int ar = row0 + r;
    if (ar >= NODES) ar = NODES - 1;
    for (int k0 = 0; k0 < K; k0 += 32) {
        s16x8 af = *(const s16x8*)(A + (size_t)ar * lda + k0 + g * 8);
        #pragma unroll
        for (int j = 0; j < 4; ++j) {
            s16x8 bf = *(const s16x8*)(WT + (size_t)(j * 16 + r) * K + k0 + g * 8);
            acc[j] = __builtin_amdgcn_mfma_f32_16x16x32_bf16(af, bf, acc[j], 0, 0, 0);
        }
    }
    float s_[4], q_[4];
    #pragma unroll
    for (int j = 0; j < 4; ++j) {
        float b = bias[j * 16 + r];
        float s = 0.0f, q = 0.0f;
        #pragma unroll
        for (int i = 0; i < 4; ++i) {
            int row = row0 + g * 4 + i;
            if (row < NODES) {
                float v = acc[j][i] + b;
                C[(size_t)row * 64 + j * 16 + r] = v;
                s += v; q += v * v;
            }
        }
        s += __shfl_xor(s, 16); s += __shfl_xor(s, 32);
        q += __shfl_xor(q, 16); q += __shfl_xor(q, 32);
        s_[j] = s; q_[j] = q;
    }
    if (g == 0) {
        #pragma unroll
        for (int j = 0; j < 4; ++j) {
            red[wave][j * 16 + r] = s_[j];
            red[wave][64 + j * 16 + r] = q_[j];
        }
    }
    __syncthreads();
    if (threadIdx.x < 128) {
        float tot = red[0][threadIdx.x] + red[1][threadIdx.x] +
                    red[2][threadIdx.x] + red[3][threadIdx.x];
        atomicAdd(&stats[threadIdx.x * 16], tot);
    }
}

// ---------------- BN finalize + ReLU (+residual), vectorized ----------------

__global__ void k_apply(const float* __restrict__ t, const float* __restrict__ stats,
                        const float* __restrict__ gamma, const float* __restrict__ beta,
                        float* __restrict__ h, __hip_bfloat16* __restrict__ AB, int residual) {
    int idx0 = blockIdx.x * blockDim.x + threadIdx.x;
    int stride = gridDim.x * blockDim.x;
    const float invN = 1.0f / NODES;
    for (int idx = idx0; idx < NODES * 16; idx += stride) {
        int n = idx >> 4;
        int j = (idx & 15) * 4;
        f32x4 tv = *(const f32x4*)(t + (size_t)n * 64 + j);
        f32x4 hv;
        if (residual) hv = *(const f32x4*)(h + (size_t)n * 64 + j);
        float out[4];
        ushort ub[4];
        #pragma unroll
        for (int k = 0; k < 4; ++k) {
            int f = j + k;
            float mu = stats[f * 16] * invN;
            float var = stats[(64 + f) * 16] * invN - mu * mu;
            float sc = gamma[f] * rsqrtf(var + BN_EPS);
            float sh = beta[f] - mu * sc;
            float v = fmaxf(tv[k] * sc + sh, 0.0f);
            out[k] = residual ? (hv[k] + v) : v;
            ub[k] = bf16bits(out[k]);
        }
        *(f32x4*)(h + (size_t)n * 64 + j) = f32x4{out[0], out[1], out[2], out[3]};
        *(ushort4*)((ushort*)AB + (size_t)n * 128 + 64 + j) = make_ushort4(ub[0], ub[1], ub[2], ub[3]);
    }
}

// ---------------- mean aggregation: 2 edges in flight per wave ----------------

__global__ void k_agg(const int* __restrict__ off, const int* __restrict__ ebuf,
                      const float* __restrict__ rdenom, __hip_bfloat16* __restrict__ ABh) {
    unsigned* AB = (unsigned*)ABh;          // view rows as 64 uints (2 bf16 each)
    int lane = threadIdx.x & 63;
    int half = lane >> 5;                   // which edge of the pair
    int fl = lane & 31;                     // feature-pair index
    int w = blockIdx.x * (blockDim.x >> 6) + (threadIdx.x >> 6);
    int nw = gridDim.x * (blockDim.x >> 6);
    for (int n = w; n < NODES; n += nw) {
        int p0 = off[n], p1 = off[n + 1];
        float a0 = 0.0f, a1 = 0.0f;
        for (int p = p0 + half; p < p1; p += 2) {
            int s = ebuf[p];
            unsigned v = AB[(size_t)s * 64 + 32 + fl];
            a0 += bf16lo(v);
            a1 += bf16hi(v);
        }
        a0 += __shfl_xor(a0, 32);
        a1 += __shfl_xor(a1, 32);
        if (half == 0) {
            float rd = rdenom[n];
            unsigned o = (unsigned)bf16bits(a0 * rd) | ((unsigned)bf16bits(a1 * rd) << 16);
            AB[(size_t)n * 64 + fl] = o;
        }
    }
}

// ---------------- launch ----------------

extern "C" void kernel_launch(void* const* d_in, const int* in_sizes, int n_in,
                              void* d_out, int out_size, void* d_ws, size_t ws_size,
                              hipStream_t stream) {
    const float* x    = (const float*)d_in[0];
    const int*   ei   = (const int*)d_in[1];
    const float* w_in = (const float*)d_in[2];
    const float* b_in = (const float*)d_in[3];
    const float* bn0g = (const float*)d_in[4];
    const float* bn0b = (const float*)d_in[5];
    const float* wl   = (const float*)d_in[6];
    const float* bl   = (const float*)d_in[7];
    const float* wr   = (const float*)d_in[8];
    const float* bng  = (const float*)d_in[9];
    const float* bnb  = (const float*)d_in[10];
    const int* esrc = ei;
    const int* edst = ei + EDGES;
    float* h = (float*)d_out;

    char* p = (char*)d_ws;
    auto alloc = [&](size_t bytes) {
        char* r = p;
        p += (bytes + 255) & ~size_t(255);
        return r;
    };
    // zeroed region
    int*   bintot = (int*)alloc((size_t)NBINS * 4);
    float* stats  = (float*)alloc((size_t)4 * 128 * 16 * 4);
    char*  zero_end = p;
    // scratch
    int2*     cb   = (int2*)alloc((size_t)NBINS * NBLK * 8);
    unsigned* bbuf = (unsigned*)alloc((size_t)NBLK * EPB * 4);
    int*   off  = (int*)alloc((size_t)(NODES + 1) * 4);
    float* rden = (float*)alloc((size_t)NODES * 4);
    int*   ebuf = (int*)alloc((size_t)EDGES * 4);
    __hip_bfloat16* xpad  = (__hip_bfloat16*)alloc((size_t)NODES * 32 * 2);
    __hip_bfloat16* WiT   = (__hip_bfloat16*)alloc(64 * 32 * 2);
    __hip_bfloat16* WcatT = (__hip_bfloat16*)alloc(LAYERS * 64 * 128 * 2);
    __hip_bfloat16* AB    = (__hip_bfloat16*)alloc((size_t)NODES * 128 * 2);
    float* t = (float*)alloc((size_t)NODES * 64 * 4);

    hipMemsetAsync(bintot, 0, (size_t)(zero_end - (char*)bintot), stream);

    k_sortA<<<NBLK, 1024, 0, stream>>>(esrc, edst, cb, bintot, bbuf);
    k_binB<<<NBINS, 512, 0, stream>>>(cb, bintot, bbuf, off, rden, ebuf);
    k_prep<<<(NODES * 32 + 255) / 256, 256, 0, stream>>>(x, w_in, wl, wr, xpad, WiT, WcatT);

    k_gemm<<<(NODES + 63) / 64, 256, 0, stream>>>(xpad, 32, WiT, 32, b_in, t, stats);
    k_apply<<<2048, 256, 0, stream>>>(t, stats, bn0g, bn0b, h, AB, 0);

    for (int l = 0; l < LAYERS; ++l) {
        k_agg<<<2048, 256, 0, stream>>>(off, ebuf, rden, AB);
        k_gemm<<<(NODES + 63) / 64, 256, 0, stream>>>(AB, 128, WcatT + l * 8192, 128,
                                                      bl + l * 64, t, stats + (l + 1) * 2048);
        k_apply<<<2048, 256, 0, stream>>>(t, stats + (l + 1) * 2048, bng + l * 64, bnb + l * 64,
                                          h, AB, 1);
    }
}

// Round 4
// 304.835 us; speedup vs baseline: 1.4469x; 1.1754x over previous
//
#include <hip/hip_runtime.h>
#include <hip/hip_bf16.h>

#define NODES 50000
#define EDGES 800000
#define DIN   19
#define HDIM  64
#define LAYERS 3
#define BN_EPS 1e-5f

#define NBINS 196          // ceil(NODES/256), bin = dst>>8
#define EPB   4096         // edges per sort block
#define NBLK  196          // ceil(EDGES/EPB)

typedef __attribute__((ext_vector_type(4))) float f32x4;
typedef __attribute__((ext_vector_type(8))) short s16x8;

__device__ inline ushort bf16bits(float f) {
    __hip_bfloat16 h = __float2bfloat16(f);
    return *reinterpret_cast<ushort*>(&h);
}
__device__ inline float bf16lo(unsigned v) { return __uint_as_float(v << 16); }
__device__ inline float bf16hi(unsigned v) { return __uint_as_float(v & 0xFFFF0000u); }

// ---------------- pass A: per-block LDS counting sort of edges by dst>>8 ----------------

__global__ __launch_bounds__(1024) void k_sortA(const int* __restrict__ src, const int* __restrict__ dst,
                                                int2* __restrict__ cb, int* __restrict__ bintot,
                                                unsigned* __restrict__ bbuf) {
    __shared__ int hist[256];
    __shared__ int cur[256];
    __shared__ int wsum4[4];
    __shared__ unsigned stage[EPB];
    int blk = blockIdx.x, t = threadIdx.x;
    int e0 = blk * EPB;
    int ne = min(EPB, EDGES - e0);
    int d[4]; unsigned pk[4];
    #pragma unroll
    for (int i = 0; i < 4; ++i) {
        int j = t + i * 1024;
        if (j < ne) {
            int dd = dst[e0 + j];
            d[i] = dd;
            pk[i] = ((unsigned)(dd & 255) << 24) | (unsigned)src[e0 + j];
        } else d[i] = -1;
    }
    if (t < 256) hist[t] = 0;
    __syncthreads();
    #pragma unroll
    for (int i = 0; i < 4; ++i)
        if (d[i] >= 0) atomicAdd(&hist[d[i] >> 8], 1);
    __syncthreads();
    int ln = t & 63, wv = t >> 6;
    int cntv = 0, inc = 0;
    if (t < 256) {
        cntv = hist[t];
        inc = cntv;
        #pragma unroll
        for (int s = 1; s < 64; s <<= 1) {
            int u = __shfl_up(inc, s);
            if (ln >= s) inc += u;
        }
        if (ln == 63) wsum4[wv] = inc;
    }
    __syncthreads();
    if (t < 256) {
        int woff = 0;
        #pragma unroll
        for (int i = 0; i < 4; ++i) if (i < wv) woff += wsum4[i];
        int excl = woff + inc - cntv;
        cur[t] = excl;
        if (t < NBINS) {
            cb[t * NBLK + blk] = make_int2(excl, cntv);
            if (cntv) atomicAdd(&bintot[t], cntv);
        }
    }
    __syncthreads();
    #pragma unroll
    for (int i = 0; i < 4; ++i)
        if (d[i] >= 0) {
            int slot = atomicAdd(&cur[d[i] >> 8], 1);
            stage[slot] = pk[i];
        }
    __syncthreads();
    #pragma unroll
    for (int i = 0; i < 4; ++i) {
        int j = t + i * 1024;
        if (j < ne) bbuf[e0 + j] = stage[j];
    }
}

// ---------------- pass B: per-bin CSR assembly ----------------

__global__ __launch_bounds__(512) void k_binB(const int2* __restrict__ cb, const int* __restrict__ bintot,
                                              const unsigned* __restrict__ bbuf,
                                              int* __restrict__ off, float* __restrict__ rdenom,
                                              int* __restrict__ ebuf) {
    __shared__ int red[256];
    __shared__ int segoff[NBINS], segcnt[NBINS];
    __shared__ int deg[256], loff[256], cur[256];
    __shared__ int wsum4[4];
    __shared__ int binoff_s;
    int b = blockIdx.x, t = threadIdx.x;
    int ln = t & 63, wv = t >> 6;
    if (t < 256) red[t] = (t < b) ? bintot[t] : 0;
    __syncthreads();
    #pragma unroll
    for (int s = 128; s > 0; s >>= 1) {
        if (t < s && t + s < 256) red[t] += red[t + s];
        __syncthreads();
    }
    if (t == 0) binoff_s = red[0];
    if (t < NBINS) {
        int2 c = cb[b * NBLK + t];
        segoff[t] = c.x; segcnt[t] = c.y;
    }
    if (t < 256) { deg[t] = 0; cur[t] = 0; }
    __syncthreads();
    int binoff = binoff_s;
    for (int sg = wv; sg < NBLK; sg += 8) {
        int c = segcnt[sg];
        const unsigned* bp = bbuf + sg * EPB + segoff[sg];
        for (int k = ln; k < c; k += 64) atomicAdd(&deg[bp[k] >> 24], 1);
    }
    __syncthreads();
    int dv = 0, inc = 0;
    if (t < 256) {
        dv = deg[t];
        inc = dv;
        #pragma unroll
        for (int s = 1; s < 64; s <<= 1) {
            int u = __shfl_up(inc, s);
            if (ln >= s) inc += u;
        }
        if (ln == 63) wsum4[wv] = inc;
    }
    __syncthreads();
    if (t < 256) {
        int woff = 0;
        #pragma unroll
        for (int i = 0; i < 4; ++i) if (i < wv) woff += wsum4[i];
        int excl = woff + inc - dv;
        loff[t] = excl;
        int node = (b << 8) + t;
        if (node < NODES) {
            off[node] = binoff + excl;
            rdenom[node] = 1.0f / fmaxf((float)dv, 1.0f);
        }
        if (b == NBINS - 1 && t == 0) off[NODES] = EDGES;
    }
    __syncthreads();
    for (int sg = wv; sg < NBLK; sg += 8) {
        int c = segcnt[sg];
        const unsigned* bp = bbuf + sg * EPB + segoff[sg];
        for (int k = ln; k < c; k += 64) {
            unsigned e = bp[k];
            int dd = e >> 24;
            int slot = atomicAdd(&cur[dd], 1);
            ebuf[binoff + loff[dd] + slot] = (int)(e & 0xFFFFFFu);
        }
    }
}

// ---------------- prep ----------------

__global__ void k_prep(const float* __restrict__ x, const float* __restrict__ w_in,
                       const float* __restrict__ wl, const float* __restrict__ wr,
                       __hip_bfloat16* __restrict__ xpad, __hip_bfloat16* __restrict__ WiT,
                       __hip_bfloat16* __restrict__ WcatT) {
    int i = blockIdx.x * blockDim.x + threadIdx.x;
    if (i < 64 * 32) {
        int c = i >> 5, k = i & 31;
        WiT[i] = __float2bfloat16(k < DIN ? w_in[k * HDIM + c] : 0.0f);
    }
    if (i < LAYERS * 64 * 128) {
        int l = i >> 13;
        int rem = i & 8191;
        int c = rem >> 7, k = rem & 127;
        float v = (k < 64) ? wl[(l * 64 + k) * 64 + c] : wr[(l * 64 + (k - 64)) * 64 + c];
        WcatT[i] = __float2bfloat16(v);
    }
    if (i < NODES * 32) {
        int n = i >> 5, k = i & 31;
        xpad[i] = __float2bfloat16(k < DIN ? x[n * DIN + k] : 0.0f);
    }
}

// ---------------- GEMM + fused BN stats, bf16 output ----------------

__global__ void k_gemm(const __hip_bfloat16* __restrict__ A, int lda,
                       const __hip_bfloat16* __restrict__ WT, int K,
                       const float* __restrict__ bias, ushort* __restrict__ tb,
                       float* __restrict__ stats) {
    __shared__ float red[4][128];
    int lane = threadIdx.x & 63, wave = threadIdx.x >> 6;
    int row0 = blockIdx.x * 64 + wave * 16;
    int r = lane & 15, g = lane >> 4;
    f32x4 acc[4] = {{0.f,0.f,0.f,0.f},{0.f,0.f,0.f,0.f},{0.f,0.f,0.f,0.f},{0.f,0.f,0.f,0.f}};
    int ar = row0 + r;
    if (ar >= NODES) ar = NODES - 1;
    for (int k0 = 0; k0 < K; k0 += 32) {
        s16x8 af = *(const s16x8*)(A + (size_t)ar * lda + k0 + g * 8);
        #pragma unroll
        for (int j = 0; j < 4; ++j) {
            s16x8 bf = *(const s16x8*)(WT + (size_t)(j * 16 + r) * K + k0 + g * 8);
            acc[j] = __builtin_amdgcn_mfma_f32_16x16x32_bf16(af, bf, acc[j], 0, 0, 0);
        }
    }
    float s_[4], q_[4];
    #pragma unroll
    for (int j = 0; j < 4; ++j) {
        float b = bias[j * 16 + r];
        float s = 0.0f, q = 0.0f;
        #pragma unroll
        for (int i = 0; i < 4; ++i) {
            int row = row0 + g * 4 + i;
            if (row < NODES) {
                float v = acc[j][i] + b;
                tb[(size_t)row * 64 + j * 16 + r] = bf16bits(v);
                s += v; q += v * v;
            }
        }
        s += __shfl_xor(s, 16); s += __shfl_xor(s, 32);
        q += __shfl_xor(q, 16); q += __shfl_xor(q, 32);
        s_[j] = s; q_[j] = q;
    }
    if (g == 0) {
        #pragma unroll
        for (int j = 0; j < 4; ++j) {
            red[wave][j * 16 + r] = s_[j];
            red[wave][64 + j * 16 + r] = q_[j];
        }
    }
    __syncthreads();
    if (threadIdx.x < 128) {
        float tot = red[0][threadIdx.x] + red[1][threadIdx.x] +
                    red[2][threadIdx.x] + red[3][threadIdx.x];
        atomicAdd(&stats[threadIdx.x * 16], tot);
    }
}

// ---------------- BN finalize + ReLU (+residual) ----------------

__global__ void k_apply(const ushort* __restrict__ tb, const float* __restrict__ stats,
                        const float* __restrict__ gamma, const float* __restrict__ beta,
                        float* __restrict__ h, __hip_bfloat16* __restrict__ AB, int residual) {
    int idx0 = blockIdx.x * blockDim.x + threadIdx.x;
    int stride = gridDim.x * blockDim.x;
    const float invN = 1.0f / NODES;
    for (int idx = idx0; idx < NODES * 16; idx += stride) {
        int n = idx >> 4;
        int j = (idx & 15) * 4;
        ushort4 tv = *(const ushort4*)(tb + (size_t)n * 64 + j);
        float tf[4] = { __uint_as_float((unsigned)tv.x << 16), __uint_as_float((unsigned)tv.y << 16),
                        __uint_as_float((unsigned)tv.z << 16), __uint_as_float((unsigned)tv.w << 16) };
        f32x4 hv;
        if (residual) hv = *(const f32x4*)(h + (size_t)n * 64 + j);
        float out[4];
        ushort ub[4];
        #pragma unroll
        for (int k = 0; k < 4; ++k) {
            int f = j + k;
            float mu = stats[f * 16] * invN;
            float var = stats[(64 + f) * 16] * invN - mu * mu;
            float sc = gamma[f] * rsqrtf(var + BN_EPS);
            float sh = beta[f] - mu * sc;
            float v = fmaxf(tf[k] * sc + sh, 0.0f);
            out[k] = residual ? (hv[k] + v) : v;
            ub[k] = bf16bits(out[k]);
        }
        *(f32x4*)(h + (size_t)n * 64 + j) = f32x4{out[0], out[1], out[2], out[3]};
        *(ushort4*)((ushort*)AB + (size_t)n * 128 + 64 + j) = make_ushort4(ub[0], ub[1], ub[2], ub[3]);
    }
}

// ---------------- mean aggregation: 8 gathers in flight per wave ----------------

__global__ void k_agg(const int* __restrict__ off, const int* __restrict__ ebuf,
                      const float* __restrict__ rdenom, __hip_bfloat16* __restrict__ ABh) {
    unsigned* AB = (unsigned*)ABh;          // rows = 64 uints (2 bf16 each)
    int lane = threadIdx.x & 63;
    int half = lane >> 5;
    int fl = lane & 31;
    int w = blockIdx.x * (blockDim.x >> 6) + (threadIdx.x >> 6);
    int nw = gridDim.x * (blockDim.x >> 6);
    for (int n = w; n < NODES; n += nw) {
        int p0 = off[n], p1 = off[n + 1];
        float a0 = 0.0f, a1 = 0.0f;
        int p = p0 + half;
        for (; p + 6 < p1; p += 8) {
            int s0 = ebuf[p];
            int s1 = ebuf[p + 2];
            int s2 = ebuf[p + 4];
            int s3 = ebuf[p + 6];
            unsigned v0 = AB[(size_t)s0 * 64 + 32 + fl];
            unsigned v1 = AB[(size_t)s1 * 64 + 32 + fl];
            unsigned v2 = AB[(size_t)s2 * 64 + 32 + fl];
            unsigned v3 = AB[(size_t)s3 * 64 + 32 + fl];
            a0 += bf16lo(v0); a1 += bf16hi(v0);
            a0 += bf16lo(v1); a1 += bf16hi(v1);
            a0 += bf16lo(v2); a1 += bf16hi(v2);
            a0 += bf16lo(v3); a1 += bf16hi(v3);
        }
        for (; p < p1; p += 2) {
            int s = ebuf[p];
            unsigned v = AB[(size_t)s * 64 + 32 + fl];
            a0 += bf16lo(v); a1 += bf16hi(v);
        }
        a0 += __shfl_xor(a0, 32);
        a1 += __shfl_xor(a1, 32);
        if (half == 0) {
            float rd = rdenom[n];
            unsigned o = (unsigned)bf16bits(a0 * rd) | ((unsigned)bf16bits(a1 * rd) << 16);
            AB[(size_t)n * 64 + fl] = o;
        }
    }
}

// ---------------- launch ----------------

extern "C" void kernel_launch(void* const* d_in, const int* in_sizes, int n_in,
                              void* d_out, int out_size, void* d_ws, size_t ws_size,
                              hipStream_t stream) {
    const float* x    = (const float*)d_in[0];
    const int*   ei   = (const int*)d_in[1];
    const float* w_in = (const float*)d_in[2];
    const float* b_in = (const float*)d_in[3];
    const float* bn0g = (const float*)d_in[4];
    const float* bn0b = (const float*)d_in[5];
    const float* wl   = (const float*)d_in[6];
    const float* bl   = (const float*)d_in[7];
    const float* wr   = (const float*)d_in[8];
    const float* bng  = (const float*)d_in[9];
    const float* bnb  = (const float*)d_in[10];
    const int* esrc = ei;
    const int* edst = ei + EDGES;
    float* h = (float*)d_out;

    char* p = (char*)d_ws;
    auto alloc = [&](size_t bytes) {
        char* r = p;
        p += (bytes + 255) & ~size_t(255);
        return r;
    };
    // zeroed region
    int*   bintot = (int*)alloc((size_t)NBINS * 4);
    float* stats  = (float*)alloc((size_t)4 * 128 * 16 * 4);
    char*  zero_end = p;
    // scratch
    int2*     cb   = (int2*)alloc((size_t)NBINS * NBLK * 8);
    unsigned* bbuf = (unsigned*)alloc((size_t)NBLK * EPB * 4);
    int*   off  = (int*)alloc((size_t)(NODES + 1) * 4);
    float* rden = (float*)alloc((size_t)NODES * 4);
    int*   ebuf = (int*)alloc((size_t)EDGES * 4);
    __hip_bfloat16* xpad  = (__hip_bfloat16*)alloc((size_t)NODES * 32 * 2);
    __hip_bfloat16* WiT   = (__hip_bfloat16*)alloc(64 * 32 * 2);
    __hip_bfloat16* WcatT = (__hip_bfloat16*)alloc(LAYERS * 64 * 128 * 2);
    __hip_bfloat16* AB    = (__hip_bfloat16*)alloc((size_t)NODES * 128 * 2);
    ushort* tb = (ushort*)alloc((size_t)NODES * 64 * 2);

    hipMemsetAsync(bintot, 0, (size_t)(zero_end - (char*)bintot), stream);

    k_sortA<<<NBLK, 1024, 0, stream>>>(esrc, edst, cb, bintot, bbuf);
    k_binB<<<NBINS, 512, 0, stream>>>(cb, bintot, bbuf, off, rden, ebuf);
    k_prep<<<(NODES * 32 + 255) / 256, 256, 0, stream>>>(x, w_in, wl, wr, xpad, WiT, WcatT);

    k_gemm<<<(NODES + 63) / 64, 256, 0, stream>>>(xpad, 32, WiT, 32, b_in, tb, stats);
    k_apply<<<2048, 256, 0, stream>>>(tb, stats, bn0g, bn0b, h, AB, 0);

    for (int l = 0; l < LAYERS; ++l) {
        k_agg<<<2048, 256, 0, stream>>>(off, ebuf, rden, AB);
        k_gemm<<<(NODES + 63) / 64, 256, 0, stream>>>(AB, 128, WcatT + l * 8192, 128,
                                                      bl + l * 64, tb, stats + (l + 1) * 2048);
        k_apply<<<2048, 256, 0, stream>>>(tb, stats + (l + 1) * 2048, bng + l * 64, bnb + l * 64,
                                          h, AB, 1);
    }
}